// Round 13
// baseline (249.387 us; speedup 1.0000x reference)
//
#include <hip/hip_runtime.h>
#include <math.h>

// Problem constants (fixed by reference)
#define NR 2048
#define MC 131072
#define DIM 64
#define KSEL 11                    // k+1 smallest kept per row
#define PPART 64                   // column partitions
#define PART_COLS (MC / PPART)     // 2048 cols per partition
#define CHUNK 128                  // cols per LDS chunk
#define NCHUNK (PART_COLS / CHUNK) // 16
#define ROWS_PER_BLOCK 64          // 4 waves x 16 rows
#define QDW 13                     // queue pair-slots per lane (13 dwords, odd -> all banks)
#define BSTRIDE 68                 // f16 col stride in LDS: 34 dwords -> 2-way banks (free)

typedef _Float16 v8h __attribute__((ext_vector_type(8)));
typedef _Float16 v4h __attribute__((ext_vector_type(4)));
typedef _Float16 v2h __attribute__((ext_vector_type(2)));
typedef float v4f __attribute__((ext_vector_type(4)));

// ---------------- prep: bnorm (fp32) + buf -> f16 ----------------
__global__ __launch_bounds__(256) void k_prep_b(const float* __restrict__ buf,
                                                _Float16* __restrict__ B16,
                                                float* __restrict__ bnorm) {
  int gid = blockIdx.x * 256 + threadIdx.x;   // 4 threads per buffer row
  int row = gid >> 2, q = gid & 3;
  const float4* src = (const float4*)(buf + (size_t)row * DIM + q * 16);
  float4 f0 = src[0], f1 = src[1], f2 = src[2], f3 = src[3];
  float s = f0.x*f0.x + f0.y*f0.y + f0.z*f0.z + f0.w*f0.w
          + f1.x*f1.x + f1.y*f1.y + f1.z*f1.z + f1.w*f1.w
          + f2.x*f2.x + f2.y*f2.y + f2.z*f2.z + f2.w*f2.w
          + f3.x*f3.x + f3.y*f3.y + f3.z*f3.z + f3.w*f3.w;
  s += __shfl_xor(s, 1);
  s += __shfl_xor(s, 2);
  if (q == 0) bnorm[row] = s;
  union { _Float16 h[16]; uint4 u[2]; } o;
  o.h[0]=(_Float16)f0.x; o.h[1]=(_Float16)f0.y; o.h[2]=(_Float16)f0.z; o.h[3]=(_Float16)f0.w;
  o.h[4]=(_Float16)f1.x; o.h[5]=(_Float16)f1.y; o.h[6]=(_Float16)f1.z; o.h[7]=(_Float16)f1.w;
  o.h[8]=(_Float16)f2.x; o.h[9]=(_Float16)f2.y; o.h[10]=(_Float16)f2.z; o.h[11]=(_Float16)f2.w;
  o.h[12]=(_Float16)f3.x; o.h[13]=(_Float16)f3.y; o.h[14]=(_Float16)f3.z; o.h[15]=(_Float16)f3.w;
  uint4* dst = (uint4*)(B16 + (size_t)row * DIM + q * 16);
  dst[0] = o.u[0]; dst[1] = o.u[1];
}

// branchless bubble-insert into sorted-ascending 11-list. Inserting any value
// >= lst[10] (incl. +inf) is a no-op (it bubbles off the end). 22 min/max ops.
__device__ __forceinline__ void bins11(float v, float lst[KSEL]) {
  float t = v;
#pragma unroll
  for (int j = 0; j < KSEL; ++j) {
    float a = fminf(lst[j], t);
    t = fmaxf(lst[j], t);
    lst[j] = a;
  }
}

// ---------------- main: MFMA + pair-packed f16 queue + sorted top-11 ---------
// D = A(bufcols) x B(xrows): C-layout gives each lane ONE x-row (n = lane&15).
// LDS-diet version: bn norms read straight from global (L2-hot) instead of
// LDS; queue pushes are pair-packed b32 (cvt_pkrtz) with an f16 packed
// sign-test deciding pair-pass. Junk halves of pushed pairs are genuine d2
// values (safe inserts); slots >= qo are guarded. 30.8 KB LDS -> 5 blocks/CU.
__global__ __launch_bounds__(256, 5) void k_main(const float* __restrict__ x,
                                                 const _Float16* __restrict__ B16,
                                                 const float* __restrict__ bnorm,
                                                 float* __restrict__ cand) {
  __shared__ __align__(16) _Float16 Bs[CHUNK * BSTRIDE];   // 17408 B
  __shared__ unsigned qmem[4][64 * QDW + 4];               // 13376 B -> 30784 B

  const int tid = threadIdx.x;
  const int w = tid >> 6, lane = tid & 63;
  const int quad = lane >> 4, l15 = lane & 15;
  const int row = blockIdx.y * ROWS_PER_BLOCK + w * 16 + l15;  // this lane's x-row
  const int pbase = blockIdx.x * PART_COLS;
  unsigned* q2 = &qmem[w][lane * QDW];          // pair-dword view

  // x fragments (B-operand: B[k = quad*8+j + 32ks][n = l15]) + exact fp32 norm
  v8h bx0, bx1;
  float xn;
  {
    const float* xr = x + (size_t)row * DIM;
    const float4* xp0 = (const float4*)(xr + quad * 8);
    float4 a0 = xp0[0], a1 = xp0[1];
    const float4* xp1 = (const float4*)(xr + 32 + quad * 8);
    float4 c0 = xp1[0], c1 = xp1[1];
    v8h h0, h1;
    h0[0]=(_Float16)a0.x; h0[1]=(_Float16)a0.y; h0[2]=(_Float16)a0.z; h0[3]=(_Float16)a0.w;
    h0[4]=(_Float16)a1.x; h0[5]=(_Float16)a1.y; h0[6]=(_Float16)a1.z; h0[7]=(_Float16)a1.w;
    h1[0]=(_Float16)c0.x; h1[1]=(_Float16)c0.y; h1[2]=(_Float16)c0.z; h1[3]=(_Float16)c0.w;
    h1[4]=(_Float16)c1.x; h1[5]=(_Float16)c1.y; h1[6]=(_Float16)c1.z; h1[7]=(_Float16)c1.w;
    bx0 = h0; bx1 = h1;
    float s = a0.x*a0.x + a0.y*a0.y + a0.z*a0.z + a0.w*a0.w
            + a1.x*a1.x + a1.y*a1.y + a1.z*a1.z + a1.w*a1.w
            + c0.x*c0.x + c0.y*c0.y + c0.z*c0.z + c0.w*c0.w
            + c1.x*c1.x + c1.y*c1.y + c1.z*c1.z + c1.w*c1.w;
    s += __shfl_xor(s, 16);   // each quad holds a disjoint 16 of the 64 k's
    s += __shfl_xor(s, 32);
    xn = s;
  }

  float lst[KSEL];   // sorted ascending; lst[10] = private threshold (d2 space)
#pragma unroll
  for (int i = 0; i < KSEL; ++i) lst[i] = __builtin_inff();
  float thrx = __builtin_inff();   // t-space: pass <=> t < thrx = thr - xn
  v2h mthr = (v2h)((_Float16)0);   // packed (-thrx, -thrx) for the sign test
  int qo = 0;                      // queue cursor (pair slots)

  // drain: 2 pair-dwords (4 values) per iteration + tighten shared threshold
  auto drain = [&]() {
    for (int i = 0; __ballot(i < qo); i += 2) {
      unsigned ua = q2[i], ub = q2[i + 1];
      v2h pa = __builtin_bit_cast(v2h, ua);
      v2h pb = __builtin_bit_cast(v2h, ub);
      bool ok0 = i < qo, ok1 = i + 1 < qo;
      float v0 = (float)pa[0] + xn, v1 = (float)pa[1] + xn;
      float v2 = (float)pb[0] + xn, v3 = (float)pb[1] + xn;
      v0 = ok0 ? v0 : __builtin_inff();
      v1 = ok0 ? v1 : __builtin_inff();
      v2 = ok1 ? v2 : __builtin_inff();
      v3 = ok1 ? v3 : __builtin_inff();
      float m = fminf(fminf(v0, v1), fminf(v2, v3));
      if (__ballot(m < lst[KSEL - 1])) {   // any lane improves its list?
        bins11(v0, lst); bins11(v1, lst);  // v >= lst[10] inserts are no-ops
        bins11(v2, lst); bins11(v3, lst);
      }
    }
    qo = 0;
    float th = fminf(lst[KSEL - 1], __shfl_xor(lst[KSEL - 1], 16));
    th = fminf(th, __shfl_xor(th, 32));
    thrx = th - xn;
    _Float16 nh = (_Float16)(-thrx);
    mthr[0] = nh; mthr[1] = nh;
  };

  // staging-prefetch registers (chunk c+1 loaded during chunk c's compute)
  const int scol = tid >> 1, shf = tid & 1;   // 2 threads/col, 32 f16 each
  union Stage { uint4 v4[4]; unsigned long long d[8]; } st;
  {
    const uint4* src = (const uint4*)(B16 + (size_t)(pbase + scol) * DIM + shf * 32);
    st.v4[0] = src[0]; st.v4[1] = src[1]; st.v4[2] = src[2]; st.v4[3] = src[3];
  }

  for (int c = 0; c < NCHUNK; ++c) {
    const int cb = pbase + c * CHUNK;
    __syncthreads();   // Bs free (all waves done with previous chunk's reads)
    {
      // 8B-aligned b64 writes (BSTRIDE=68 -> byte stride 136, 8B-aligned)
      unsigned long long* dst8 = (unsigned long long*)(Bs + scol * BSTRIDE + shf * 32);
#pragma unroll
      for (int j = 0; j < 8; ++j) dst8[j] = st.d[j];
    }
    __syncthreads();   // staged

    // issue next chunk's loads now; latency hides behind scan+drain below
    if (c + 1 < NCHUNK) {
      const int nb = cb + CHUNK;
      const uint4* src = (const uint4*)(B16 + (size_t)(nb + scol) * DIM + shf * 32);
      st.v4[0] = src[0]; st.v4[1] = src[1]; st.v4[2] = src[2]; st.v4[3] = src[3];
    }

    if (c == 0) {
      // warm-up: threshold is +inf, every candidate would pass -- insert
      // directly (no queue, no ballots), then establish the threshold.
#pragma unroll
      for (int mt = 0; mt < 8; ++mt) {
        const _Float16* bp = Bs + (mt * 16 + l15) * BSTRIDE + quad * 8;
        v4h lo0 = *(const v4h*)bp;
        v4h hi0 = *(const v4h*)(bp + 4);
        v4h lo1 = *(const v4h*)(bp + 32);
        v4h hi1 = *(const v4h*)(bp + 36);
        v8h a0 = __builtin_shufflevector(lo0, hi0, 0, 1, 2, 3, 4, 5, 6, 7);
        v8h a1 = __builtin_shufflevector(lo1, hi1, 0, 1, 2, 3, 4, 5, 6, 7);
        v4f acc = (v4f)(0.0f);
        acc = __builtin_amdgcn_mfma_f32_16x16x32_f16(a0, bx0, acc, 0, 0, 0);
        acc = __builtin_amdgcn_mfma_f32_16x16x32_f16(a1, bx1, acc, 0, 0, 0);
        float4 bn4 = *(const float4*)(bnorm + cb + mt * 16 + quad * 4);  // global, L2-hot
        bins11(fmaf(acc[0], -2.0f, bn4.x + xn), lst);
        bins11(fmaf(acc[1], -2.0f, bn4.y + xn), lst);
        bins11(fmaf(acc[2], -2.0f, bn4.z + xn), lst);
        bins11(fmaf(acc[3], -2.0f, bn4.w + xn), lst);
      }
      float th = fminf(lst[KSEL - 1], __shfl_xor(lst[KSEL - 1], 16));
      th = fminf(th, __shfl_xor(th, 32));
      thrx = th - xn;
      _Float16 nh = (_Float16)(-thrx);
      mthr[0] = nh; mthr[1] = nh;
    } else {
#pragma unroll
      for (int mt = 0; mt < 8; ++mt) {
        // insurance: guarantee room for this mt's <=2 pair pushes (never
        // fires post-warm-up: wave-max pair count stays far below QDW)
        if (__ballot(qo > QDW - 2)) drain();
        const _Float16* bp = Bs + (mt * 16 + l15) * BSTRIDE + quad * 8;
        v4h lo0 = *(const v4h*)bp;
        v4h hi0 = *(const v4h*)(bp + 4);
        v4h lo1 = *(const v4h*)(bp + 32);
        v4h hi1 = *(const v4h*)(bp + 36);
        v8h a0 = __builtin_shufflevector(lo0, hi0, 0, 1, 2, 3, 4, 5, 6, 7);
        v8h a1 = __builtin_shufflevector(lo1, hi1, 0, 1, 2, 3, 4, 5, 6, 7);
        v4f acc = (v4f)(0.0f);
        acc = __builtin_amdgcn_mfma_f32_16x16x32_f16(a0, bx0, acc, 0, 0, 0);
        acc = __builtin_amdgcn_mfma_f32_16x16x32_f16(a1, bx1, acc, 0, 0, 0);
        float4 bn4 = *(const float4*)(bnorm + cb + mt * 16 + quad * 4);  // global, L2-hot
        float t0 = fmaf(acc[0], -2.0f, bn4.x);   // d2 = t + xn
        float t1 = fmaf(acc[1], -2.0f, bn4.y);
        float t2 = fmaf(acc[2], -2.0f, bn4.z);
        float t3 = fmaf(acc[3], -2.0f, bn4.w);
        // pair-packed push: sign bits of (t - thrx) in f16 decide pair-pass
        v2h pk0 = __builtin_bit_cast(v2h, __builtin_amdgcn_cvt_pkrtz(t0, t1));
        v2h pk1 = __builtin_bit_cast(v2h, __builtin_amdgcn_cvt_pkrtz(t2, t3));
        unsigned s0 = __builtin_bit_cast(unsigned, (v2h)(pk0 + mthr));
        unsigned s1 = __builtin_bit_cast(unsigned, (v2h)(pk1 + mthr));
        q2[qo] = __builtin_bit_cast(unsigned, pk0);
        qo += ((s0 & 0x80008000u) != 0) ? 1 : 0;
        q2[qo] = __builtin_bit_cast(unsigned, pk1);
        qo += ((s1 & 0x80008000u) != 0) ? 1 : 0;
      }
      if (__ballot(qo > 0)) drain();
    }
  }

  // merge the 4 quads' sorted lists (disjoint col subsets of the same row)
#pragma unroll
  for (int s = 16; s <= 32; s <<= 1) {
    float other[KSEL];
#pragma unroll
    for (int j = 0; j < KSEL; ++j) other[j] = __shfl_xor(lst[j], s);
#pragma unroll
    for (int j = 0; j < KSEL; ++j) bins11(other[j], lst);
  }

  if (quad == 0) {   // one writer per row: cand layout [row][part][k], sorted
    float* dst = cand + (size_t)row * (PPART * KSEL) + blockIdx.x * KSEL;
#pragma unroll
    for (int i = 0; i < KSEL; ++i) dst[i] = lst[i];
  }
}

// ---------------- merge: wave per row, 704 = 64 lanes x 11 ----------------
__global__ __launch_bounds__(256) void k_merge(const float* __restrict__ cand,
                                               float* __restrict__ out) {
  int w = threadIdx.x >> 6, lane = threadIdx.x & 63;
  int row = blockIdx.x * 4 + w;
  const float* src = cand + (size_t)row * (PPART * KSEL) + lane * KSEL;
  float lst[KSEL];
#pragma unroll
  for (int i = 0; i < KSEL; ++i) lst[i] = src[i];
#pragma unroll
  for (int s = 1; s <= 32; s <<= 1) {
    float other[KSEL];
#pragma unroll
    for (int j = 0; j < KSEL; ++j) other[j] = __shfl_xor(lst[j], s);
#pragma unroll
    for (int j = 0; j < KSEL; ++j) bins11(other[j], lst);
  }
  if (lane == 0) {
    // lst sorted ascending: lst[0] is the self-match -> dropped
    float s = 0.0f;
#pragma unroll
    for (int j = 1; j < KSEL; ++j) s += sqrtf(fmaxf(lst[j], 0.0f));
    out[row] = log1pf(s * 0.1f);      // mean over k=10, log1p
  }
}

extern "C" void kernel_launch(void* const* d_in, const int* in_sizes, int n_in,
                              void* d_out, int out_size, void* d_ws, size_t ws_size,
                              hipStream_t stream) {
  (void)in_sizes; (void)n_in; (void)out_size; (void)ws_size;
  const float* x   = (const float*)d_in[0];   // 2048 x 64
  const float* buf = (const float*)d_in[1];   // 131072 x 64
  float* out = (float*)d_out;

  char* ws = (char*)d_ws;
  _Float16* B16 = (_Float16*)ws;                       // 16,777,216 B
  float* bnorm  = (float*)(ws + 16777216);             //    524,288 B
  float* cand   = (float*)(ws + 17301504);             //  5,767,168 B

  k_prep_b<<<dim3(2048), dim3(256), 0, stream>>>(buf, B16, bnorm);
  k_main<<<dim3(PPART, NR / ROWS_PER_BLOCK), dim3(256), 0, stream>>>(x, B16, bnorm, cand);
  k_merge<<<dim3(NR / 4), dim3(256), 0, stream>>>(cand, out);
}